// Round 12
// baseline (310.463 us; speedup 1.0000x reference)
//
#include <hip/hip_runtime.h>
#include <hip/hip_bf16.h>
#include <stdint.h>

#define B_ROWS 16384
#define K_DIM  2048   // IN + H
#define H_DIM  1024
#define N_DIM  4096   // 4*H
#define KB     (K_DIM * 2)      // bytes per packed row (4096)
#define NT     (K_DIM / 64)     // 32 K-tiles of BK=64
#define BUF0   0u
#define BUF1   65536u           // LDS double buffer: A 32K + B 32K each

using f32x4  = __attribute__((ext_vector_type(4))) float;
using bf16x8 = __attribute__((ext_vector_type(8))) __bf16;

// RNE float -> bf16 (inputs are finite)
__device__ __forceinline__ unsigned short f2bf(float f) {
    union { float f; unsigned u; } v; v.f = f;
    unsigned r = v.u + 0x7fffu + ((v.u >> 16) & 1u);
    return (unsigned short)(r >> 16);
}

// async global->LDS, 16B/lane. LDS dest must be wave-uniform (HW adds lane*16).
__device__ __forceinline__ void gload16(const void* g, const void* l) {
    __builtin_amdgcn_global_load_lds(
        (const __attribute__((address_space(1))) void*)g,
        (__attribute__((address_space(3))) void*)l,
        16, 0, 0);
}

__device__ __forceinline__ float rcp1p(float e) {   // 1/(1+e)
    return __builtin_amdgcn_rcpf(1.f + e);
}

// ---------------- pack kernels (unchanged, verified) ----------------
__global__ void pack_a_kernel(const float* __restrict__ x, const float* __restrict__ h0,
                              unsigned short* __restrict__ A) {
    int tid = blockIdx.x * 256 + threadIdx.x;
    int64_t idx = (int64_t)tid * 4;
    int b = (int)(idx >> 11);
    int k = (int)(idx & 2047);
    const float* src = (k < 1024) ? (x + (int64_t)b * 1024 + k)
                                  : (h0 + (int64_t)b * 1024 + (k - 1024));
    float4 v = *(const float4*)src;
    ushort4 o;
    o.x = f2bf(v.x); o.y = f2bf(v.y); o.z = f2bf(v.z); o.w = f2bf(v.w);
    *(ushort4*)(A + idx) = o;
}

__global__ void pack_w_kernel(const float* __restrict__ wi, const float* __restrict__ wh,
                              const float* __restrict__ bi, const float* __restrict__ bh,
                              unsigned short* __restrict__ W, float* __restrict__ bias) {
    int tid = blockIdx.x * 256 + threadIdx.x;
    int64_t idx = (int64_t)tid * 4;
    int r = (int)(idx >> 11);
    int k = (int)(idx & 2047);
    int h = r >> 2, g = r & 3;
    const float* src = (k < 1024)
        ? (wi + (int64_t)g * 1048576 + (int64_t)h * 1024 + k)
        : (wh + (int64_t)g * 1048576 + (int64_t)h * 1024 + (k - 1024));
    float4 v = *(const float4*)src;
    ushort4 o;
    o.x = f2bf(v.x); o.y = f2bf(v.y); o.z = f2bf(v.z); o.w = f2bf(v.w);
    *(ushort4*)(W + idx) = o;
    if (k == 0) bias[r] = bi[g * 1024 + h] + bh[g * 1024 + h];
}

// ------ 256x256 GEMM: literal 8-phase quadrant template (unfenced) + fused epilogue ------
// LDS (x2 @ 0/65536): A kk0 @0, A kk1 @16384, B kk0 @32768, B kk1 @49152. st_16x32
// swizzle + inverse-swizzled staging source: IDENTICAL to verified r2..r11.
// Iteration = 2 K-tiles (even->BUF0, odd->BUF1), 8 phases. Phase p (template-literal):
//   { ds_reads; stage slot; [lgkm8 if 12 reads]; s_barrier; lgkm0; setprio1;
//     16 MFMA (one C-quadrant x K=64); setprio0; [vmcnt(4) at ph4/ph8]; s_barrier }
// Quadrants: ph1 Q00 (mf0-3 x nf0-1, rd A-lo 8 + B-lo 4), ph2 Q01 (rd B-hi 4),
//   ph3 Q10 (rd A-hi 8 into SAME aA bank), ph4 Q11 (rd 0; bL cached from ph1).
// Stage ring (4-gload slots at region-death points, Δ=2 tiles):
//   ph1: B(t+1)->BUF1   ph4: A(t+2)->BUF0   ph5: B(t+2)->BUF0   ph8: A(t+3)->BUF1
// Hazard ledger:
//  RAW ph5 reads B(t+1): staged ph1; vmcnt(4)@ph4 (12 outstanding -> 4: drains
//      A(t1-carry)+ph1) before BAR2(ph4) < ph5 reads. A(t+1): staged prev ph8,
//      drained same wait. OK
//  RAW ph1' reads A,B(t+2): staged ph4,ph5; vmcnt(4)@ph8 (12 -> 4: drains ph4+ph5,
//      keeps ph8's A(t+3)) before BAR2(ph8) < ph1' reads. OK
//  WAR  every stage follows BAR2 of its region's last-read phase (A dead ph3 ->
//      staged ph4; B dead ph2 -> staged ph5/ph1'); reads retire at lgkm0 before
//      their MFMA, hence before that BAR2. OK
//  reg-WAR ph3 overwrites aA while ph2's MFMA may be in flight: HW scoreboard
//      (r5/r6 precedent, refcheck'd). bL lives ph1->ph4 (no re-read).
// NO compiler fences in the loop: only the two vm-waits carry "memory" (RAW-
// critical); lgkm waits and barriers are bare so the scheduler may float reads
// and address VALU into MFMA regions (the m201/m97 compiler-freedom path).

#define BAR     __builtin_amdgcn_s_barrier()
#define LGKM0   asm volatile("s_waitcnt lgkmcnt(0)")
#define LGKM8   asm volatile("s_waitcnt lgkmcnt(8)")
#define VM4M    asm volatile("s_waitcnt vmcnt(4)" ::: "memory")
#define SP1     __builtin_amdgcn_s_setprio(1)
#define SP0     __builtin_amdgcn_s_setprio(0)

__global__ __launch_bounds__(512, 2) void lstm_gemm_fused(
    const unsigned short* __restrict__ A, const unsigned short* __restrict__ W,
    const float* __restrict__ bias, const float* __restrict__ c0,
    float* __restrict__ ht, float* __restrict__ ct)
{
    __shared__ char sm[131072];

    const int tid = threadIdx.x;
    const int l   = tid & 63;
    const int w   = tid >> 6;         // wave 0..7
    const int wm  = w >> 2;           // 0..1  (row half: 128 rows)
    const int wn  = w & 3;            // 0..3  (col quarter: 64 cols)

    // XCD-aware bijective swizzle (1024 blocks, %8==0)
    const int bid = blockIdx.x;
    const int nid = (bid & 7) * 128 + (bid >> 3);
    const int bm  = nid >> 4;         // 0..63 (M tiles)
    const int bn  = nid & 15;         // 0..15 (N tiles)

    f32x4 acc[8][4];
#pragma unroll
    for (int i = 0; i < 8; ++i)
#pragma unroll
        for (int j = 0; j < 4; ++j) acc[i][j] = (f32x4){0.f, 0.f, 0.f, 0.f};

    // ---- staging source addressing (inverse-swizzled), pointer-bumped per iter ----
    const int srow = w * 16 + (l >> 2);                 // 0..127
    const int scb  = ((l & 3) << 4) ^ (l & 32);
    const char* Asrc = (const char*)A + (size_t)(bm * 256 + srow) * KB + scb;
    const char* Wsrc = (const char*)W + (size_t)(bn * 256 + srow) * KB + scb;
    const uint32_t wL = (uint32_t)w * 1024u;            // wave-uniform LDS dest part

    // one kk-half (2 gloads: rows 0-127, 128-255) at source byte offset SOFF
#define STAGE_A2(SOFF, KK, BOFF) do { \
    gload16(Asrc + (SOFF) + (KK) * 64,            sm + (BOFF) + (KK) * 16384u + wL); \
    gload16(Asrc + (SOFF) + (KK) * 64 + 128 * KB, sm + (BOFF) + (KK) * 16384u + 8192u + wL); \
} while (0)
#define STAGE_B2(SOFF, KK, BOFF) do { \
    gload16(Wsrc + (SOFF) + (KK) * 64,            sm + (BOFF) + 32768u + (KK) * 16384u + wL); \
    gload16(Wsrc + (SOFF) + (KK) * 64 + 128 * KB, sm + (BOFF) + 32768u + (KK) * 16384u + 8192u + wL); \
} while (0)

    // ---- fragment read addressing (swizzled, r5-verified) ----
    const int rr = l & 15, kg = l >> 4;
    const uint32_t loff = (uint32_t)rr * 64u + (((uint32_t)kg * 16u) ^ (uint32_t)((rr & 8) << 2));
    const uint32_t Ard = (uint32_t)wm * 8192u + loff;             // + BOFF + KK*16384 + mf*1024
    const uint32_t Brd = 32768u + (uint32_t)wn * 4096u + loff;    // + BOFF + KK*16384 + nf*1024

    bf16x8 aA0[4], aA1[4], bL0[2], bL1[2], bH0[2], bH1[2];

#define RD_A4(BOFF, KK, MB, ARR) do { \
    _Pragma("unroll") \
    for (int i_ = 0; i_ < 4; ++i_) \
        ARR[i_] = *(const bf16x8*)(sm + (BOFF) + (KK) * 16384u + Ard + ((MB) + i_) * 1024u); \
} while (0)
#define RD_B2(BOFF, KK, NB, BRR) do { \
    _Pragma("unroll") \
    for (int i_ = 0; i_ < 2; ++i_) \
        BRR[i_] = *(const bf16x8*)(sm + (BOFF) + (KK) * 16384u + Brd + ((NB) + i_) * 1024u); \
} while (0)

    // one C-quadrant x K=64: 16 MFMA (kk0 cluster then kk1 cluster; no dependent adjacency)
#define MMQ(MB, NB, BRR0, BRR1) do { \
    _Pragma("unroll") \
    for (int mf_ = 0; mf_ < 4; ++mf_) \
        _Pragma("unroll") \
        for (int nf_ = 0; nf_ < 2; ++nf_) \
            acc[(MB) + mf_][(NB) + nf_] = __builtin_amdgcn_mfma_f32_16x16x32_bf16( \
                aA0[mf_], BRR0[nf_], acc[(MB) + mf_][(NB) + nf_], 0, 0, 0); \
    _Pragma("unroll") \
    for (int mf_ = 0; mf_ < 4; ++mf_) \
        _Pragma("unroll") \
        for (int nf_ = 0; nf_ < 2; ++nf_) \
            acc[(MB) + mf_][(NB) + nf_] = __builtin_amdgcn_mfma_f32_16x16x32_bf16( \
                aA1[mf_], BRR1[nf_], acc[(MB) + mf_][(NB) + nf_], 0, 0, 0); \
} while (0)

    // ---- prologue: A(t0), B(t0), A(t1); drain t0; DO NOT bump ----
    STAGE_A2(0, 0, BUF0); STAGE_A2(0, 1, BUF0);
    STAGE_B2(0, 0, BUF0); STAGE_B2(0, 1, BUF0);
    STAGE_A2(128, 0, BUF1); STAGE_A2(128, 1, BUF1);
    VM4M;                               // drains A(t0)+B(t0); keeps A(t1) in flight
    BAR;

    // ---- main loop: 16 iterations x 2 K-tiles ----
#pragma unroll 1
    for (int it = 0; it < NT / 2; ++it) {
        // ===== even tile (BUF0) =====
        // ph1: Q00
        RD_A4(BUF0, 0, 0, aA0); RD_A4(BUF0, 1, 0, aA1);
        RD_B2(BUF0, 0, 0, bL0); RD_B2(BUF0, 1, 0, bL1);
        STAGE_B2(128, 0, BUF1); STAGE_B2(128, 1, BUF1);   // B(t+1)
        LGKM8; BAR; LGKM0; SP1; MMQ(0, 0, bL0, bL1); SP0; BAR;
        // ph2: Q01
        RD_B2(BUF0, 0, 2, bH0); RD_B2(BUF0, 1, 2, bH1);
        BAR; LGKM0; SP1; MMQ(0, 2, bH0, bH1); SP0; BAR;
        // ph3: Q10 (A-hi overwrites aA bank)
        RD_A4(BUF0, 0, 4, aA0); RD_A4(BUF0, 1, 4, aA1);
        BAR; LGKM0; SP1; MMQ(4, 2, bH0, bH1); SP0; BAR;
        // ph4: Q11 (bL cached from ph1)
        STAGE_A2(256, 0, BUF0); STAGE_A2(256, 1, BUF0);   // A(t+2)
        BAR; LGKM0; SP1; MMQ(4, 0, bL0, bL1); SP0; VM4M; BAR;

        // ===== odd tile (BUF1) =====
        // ph5: Q00
        RD_A4(BUF1, 0, 0, aA0); RD_A4(BUF1, 1, 0, aA1);
        RD_B2(BUF1, 0, 0, bL0); RD_B2(BUF1, 1, 0, bL1);
        STAGE_B2(256, 0, BUF0); STAGE_B2(256, 1, BUF0);   // B(t+2)
        LGKM8; BAR; LGKM0; SP1; MMQ(0, 0, bL0, bL1); SP0; BAR;
        // ph6: Q01
        RD_B2(BUF1, 0, 2, bH0); RD_B2(BUF1, 1, 2, bH1);
        BAR; LGKM0; SP1; MMQ(0, 2, bH0, bH1); SP0; BAR;
        // ph7: Q10
        RD_A4(BUF1, 0, 4, aA0); RD_A4(BUF1, 1, 4, aA1);
        BAR; LGKM0; SP1; MMQ(4, 2, bH0, bH1); SP0; BAR;
        // ph8: Q11
        STAGE_A2(384, 0, BUF1); STAGE_A2(384, 1, BUF1);   // A(t+3)
        BAR; LGKM0; SP1; MMQ(4, 0, bL0, bL1); SP0; VM4M; BAR;

        Asrc += 256; Wsrc += 256;
        // (tail iters stage in-d_ws garbage past K end; never consumed)
    }

    // ---- fused LSTM epilogue (r5-verified) ----
    asm volatile("s_waitcnt vmcnt(0) lgkmcnt(0)" ::: "memory");
    BAR;

    float* ep = (float*)(void*)sm + w * 1088;   // 16 rows x 68 floats per wave
    const int hbase = bn * 64 + wn * 16;
    const int rbase = bm * 256 + wm * 128;

#pragma unroll
    for (int mf = 0; mf < 8; ++mf) {
        // scatter acc slice (16 rows x 64 cols) to LDS, padded stride 68
#pragma unroll
        for (int nf = 0; nf < 4; ++nf)
#pragma unroll
            for (int r = 0; r < 4; ++r)
                ep[((l >> 4) * 4 + r) * 68 + nf * 16 + (l & 15)] = acc[mf][nf][r];

        // gather: lane -> (row, h); cols 4h..4h+3 = gates f,i,o,g
#pragma unroll
        for (int itr = 0; itr < 4; ++itr) {
            const int row = (l >> 4) + itr * 4;
            const int hs  = l & 15;
            f32x4 z = *(const f32x4*)(ep + row * 68 + hs * 4);
            const int hg = hbase + hs;
            const float4 bz = ((const float4*)bias)[hg];
            const int brow = rbase + mf * 16 + row;

            float zf = z.x + bz.x;
            float zi = z.y + bz.y;
            float zo = z.z + bz.z;
            float zg = z.w + bz.w;

            float fg = rcp1p(__expf(-zf));                   // sigmoid
            float ig = rcp1p(__expf(-zi));
            float og = rcp1p(__expf(-zo));
            float gg = 2.f * rcp1p(__expf(-2.f * zg)) - 1.f; // tanh

            int64_t oi = (int64_t)brow * H_DIM + hg;
            float c  = fg * c0[oi] + ig * gg;
            float hh = og * (2.f * rcp1p(__expf(-2.f * c)) - 1.f);
            ct[oi] = c;
            ht[oi] = hh;
        }
    }
}

extern "C" void kernel_launch(void* const* d_in, const int* in_sizes, int n_in,
                              void* d_out, int out_size, void* d_ws, size_t ws_size,
                              hipStream_t stream) {
    const float* x  = (const float*)d_in[0];
    const float* h0 = (const float*)d_in[1];
    const float* c0 = (const float*)d_in[2];
    const float* wi = (const float*)d_in[3];
    const float* bi = (const float*)d_in[4];
    const float* wh = (const float*)d_in[5];
    const float* bh = (const float*)d_in[6];

    float* ht = (float*)d_out;
    float* ct = ht + (int64_t)B_ROWS * H_DIM;

    char* ws = (char*)d_ws;
    unsigned short* A  = (unsigned short*)ws;                       // 64 MiB
    unsigned short* Wp = (unsigned short*)(ws + (64u << 20));       // 16 MiB
    float*          bs = (float*)(ws + (80u << 20));                // 16 KiB

    pack_a_kernel<<<32768, 256, 0, stream>>>(x, h0, A);
    pack_w_kernel<<<8192, 256, 0, stream>>>(wi, wh, bi, bh, Wp, bs);

    lstm_gemm_fused<<<1024, 512, 0, stream>>>(A, Wp, bs, c0, ht, ct);
}